// Round 21
// baseline (247.296 us; speedup 1.0000x reference)
//
#include <hip/hip_runtime.h>

#define D_IN 150528
#define FEAT 256
#define HID 64
#define T 4
#define B 8
#define NROWS 1280            // 5 * 256 rows (W1 + 4x dW1)
#define D4 37632              // D_IN / 4 float4 per row
#define KS 21                 // K splits (bracketed: 7->265us, 21->219, 42->320)
#define JSTEPS 28             // 588 / 21 (64-float4 steps per chunk)
#define RPW 4                 // rows per wave
#define RPB 16                // rows per block (4 waves)
#define NRB 80                // 1280 / 16
#define NBLK (KS * NRB)       // 1680 = 8 * 210

typedef float f4 __attribute__((ext_vector_type(4)));

// ---------------- stage 1: the 5 batched GEMVs over K=150528 ----------------
// r20 structure with ONE change: matrix loads are PLAIN (NT hint dropped).
// A/B from history: non-NT clean (r2) FETCH=411MB (L2/L3 retain ~350MB of
// the matrix across graph replays); NT (r12) FETCH=724MB. NT was added to
// protect x's L2 residency, but the XCD swizzle now does that by construction
// -> NT is pure cost (~300MB extra HBM/replay ~ 50-75us).
__global__ __launch_bounds__(256, 4) void stage1(
    const float* __restrict__ x, const float* __restrict__ W1,
    const float* __restrict__ dW1, float* __restrict__ partial) {
  const int bid  = blockIdx.x;                        // 0..1679
  const int vid  = (bid & 7) * (NBLK / 8) + (bid >> 3); // bijective, 1680%8==0
  const int ks   = vid / NRB;                         // 0..20 (XCD-banded)
  const int rb   = vid % NRB;                         // 0..79
  const int wid  = threadIdx.x >> 6;                  // wave 0..3
  const int lane = threadIdx.x & 63;
  // wave-uniform row base -> SGPR
  const int r0   = __builtin_amdgcn_readfirstlane(rb * RPB + wid * RPW);
  const int kb4  = ks * (JSTEPS * 64);                // float4 offset in K

  const f4* rp[RPW];                                  // wave-uniform -> SGPRs
#pragma unroll
  for (int i = 0; i < RPW; ++i) {
    int r = r0 + i, m = r >> 8, f = r & 255;
    const float* base = (m == 0) ? (W1 + (size_t)f * D_IN)
                                 : (dW1 + ((size_t)(m - 1) * FEAT + f) * D_IN);
    rp[i] = (const f4*)base + kb4;
  }
  const f4* x4 = (const f4*)x + kb4;                  // + b*D4 + idx

  float acc[RPW][B];
#pragma unroll
  for (int i = 0; i < RPW; ++i)
#pragma unroll
    for (int b = 0; b < B; ++b) acc[i][b] = 0.f;

  for (int j = 0; j < JSTEPS; ++j) {
    const int idx = j * 64 + lane;
    f4 mv[RPW];
#pragma unroll
    for (int i = 0; i < RPW; ++i) mv[i] = rp[i][idx]; // 4x 1KB HBM streams
#pragma unroll
    for (int b = 0; b < B; ++b) {                     // one xv live at a time
      f4 xv = x4[(size_t)b * D4 + idx];               // L2-resident (swizzle)
#pragma unroll
      for (int i = 0; i < RPW; ++i)
        acc[i][b] += mv[i][0] * xv[0] + mv[i][1] * xv[1] +
                     mv[i][2] * xv[2] + mv[i][3] * xv[3];
    }
  }

  // full-wave butterfly per (i,b); lanes 0..31 keep (row i=lane>>3, b=lane&7)
  float outv = 0.f;
#pragma unroll
  for (int i = 0; i < RPW; ++i)
#pragma unroll
    for (int b = 0; b < B; ++b) {
      float v = acc[i][b];
      v += __shfl_xor(v, 1);
      v += __shfl_xor(v, 2);
      v += __shfl_xor(v, 4);
      v += __shfl_xor(v, 8);
      v += __shfl_xor(v, 16);
      v += __shfl_xor(v, 32);
      if (lane == i * B + b) outv = v;                // compile-time acc index
    }
  if (lane < RPW * B)                                 // 32 consecutive floats
    partial[((size_t)ks * NROWS + r0) * B + lane] = outv;
}

// ------- stage 3: K-split reduce + everything after hpre, 1 block/batch -----
__global__ __launch_bounds__(256) void stage3(
    const float* __restrict__ P, const float* __restrict__ b1,
    const float* __restrict__ db1, const float* __restrict__ W2,
    const float* __restrict__ b2, const float* __restrict__ mW1,
    const float* __restrict__ mb1, const float* __restrict__ mW2,
    const float* __restrict__ mb2, const float* __restrict__ dW2,
    const float* __restrict__ db2, float* __restrict__ out) {
  __shared__ float hp_l[NROWS];                       // 5 KB
  __shared__ float h_l[FEAT];
  __shared__ float base_l[FEAT];
  __shared__ float u_l[FEAT];
  __shared__ float mid_l[HID];
  __shared__ float c_l[T];
  const int b = blockIdx.x;                           // batch
  const int g = threadIdx.x;                          // feature

  // hp[r] for this batch: bias + sum over K-splits
#pragma unroll
  for (int k = 0; k < NROWS / 256; ++k) {             // 5 rows/thread
    int r = k * 256 + g;
    float s = (r < FEAT) ? b1[r] : db1[r - FEAT];
#pragma unroll
    for (int ks = 0; ks < KS; ++ks)
      s += P[((size_t)ks * NROWS + r) * B + b];
    hp_l[r] = s;
  }
  __syncthreads();

  const float hpre = hp_l[g];
  h_l[g] = hpre > 0.f ? hpre : 0.f;
  __syncthreads();

  // base[g] = b2[g] + h·W2[g]
  const float4* h4 = (const float4*)h_l;
  const float4* w4 = (const float4*)(W2 + (size_t)g * FEAT);
  {
    float s = b2[g];
    for (int f4i = 0; f4i < FEAT / 4; ++f4i) {
      float4 hh = h4[f4i], w = w4[f4i];
      s += hh.x * w.x + hh.y * w.y + hh.z * w.z + hh.w * w.w;
    }
    base_l[g] = s;
  }
  __syncthreads();

  // mid[hid] = relu(mb1 + base·mW1[hid])   (threads 0..63)
  if (g < HID) {
    float s = mb1[g];
    const float4* b4 = (const float4*)base_l;
    const float4* mw = (const float4*)(mW1 + (size_t)g * FEAT);
    for (int f4i = 0; f4i < FEAT / 4; ++f4i) {
      float4 bb = b4[f4i], w = mw[f4i];
      s += bb.x * w.x + bb.y * w.y + bb.z * w.z + bb.w * w.w;
    }
    mid_l[g] = s > 0.f ? s : 0.f;
  }
  __syncthreads();

  // coefs[t]   (threads 0..3)
  if (g < T) {
    float s = mb2[g];
    const float* wrow = mW2 + g * HID;
    for (int hh = 0; hh < HID; ++hh) s += mid_l[hh] * wrow[hh];
    c_l[g] = s;
  }
  __syncthreads();

  // u[g] = (hpre>0) * sum_t c[t]*dhpre[t][g]
  {
    float s = 0.f;
    if (hpre > 0.f) {
#pragma unroll
      for (int t = 0; t < T; ++t)
        s += c_l[t] * hp_l[(1 + t) * FEAT + g];
    }
    u_l[g] = s;
  }
  __syncthreads();

  // out[b][g] = base + sum_t c*db2 + u·W2[g] + sum_t c_t*(h·dW2[t][g])
  float o = base_l[g];
#pragma unroll
  for (int t = 0; t < T; ++t) o += c_l[t] * db2[t * FEAT + g];
  const float4* u4 = (const float4*)u_l;
  float a1 = 0.f;
  float a2[T] = {0.f, 0.f, 0.f, 0.f};
  for (int f4i = 0; f4i < FEAT / 4; ++f4i) {
    float4 w = w4[f4i], uu = u4[f4i], hh = h4[f4i];
    a1 += uu.x * w.x + uu.y * w.y + uu.z * w.z + uu.w * w.w;
#pragma unroll
    for (int t = 0; t < T; ++t) {
      float4 dv = ((const float4*)(dW2 + (((size_t)t * FEAT) + g) * FEAT))[f4i];
      a2[t] += hh.x * dv.x + hh.y * dv.y + hh.z * dv.z + hh.w * dv.w;
    }
  }
  o += a1;
#pragma unroll
  for (int t = 0; t < T; ++t) o += c_l[t] * a2[t];
  out[b * FEAT + g] = o;
}

extern "C" void kernel_launch(void* const* d_in, const int* in_sizes, int n_in,
                              void* d_out, int out_size, void* d_ws, size_t ws_size,
                              hipStream_t stream) {
  const float* x   = (const float*)d_in[0];
  const float* W1  = (const float*)d_in[1];
  const float* b1  = (const float*)d_in[2];
  const float* W2  = (const float*)d_in[3];
  const float* b2  = (const float*)d_in[4];
  const float* mW1 = (const float*)d_in[5];
  const float* mb1 = (const float*)d_in[6];
  const float* mW2 = (const float*)d_in[7];
  const float* mb2 = (const float*)d_in[8];
  const float* dW1 = (const float*)d_in[9];
  const float* db1 = (const float*)d_in[10];
  const float* dW2 = (const float*)d_in[11];
  const float* db2 = (const float*)d_in[12];
  float* out = (float*)d_out;

  float* ws = (float*)d_ws;
  float* P  = ws;                              // [21][1280][8] = 215040

  stage1<<<NBLK, 256, 0, stream>>>(x, W1, dW1, P);
  stage3<<<B, 256, 0, stream>>>(P, b1, db1, W2, b2, mW1, mb1, mW2, mb2,
                                dW2, db2, out);
}

// Round 22
// 191.075 us; speedup vs baseline: 1.2942x; 1.2942x over previous
//
#include <hip/hip_runtime.h>

#define D_IN 150528
#define FEAT 256
#define HID 64
#define T 4
#define B 8
#define NROWS 1280            // 5 * 256 rows (W1 + 4x dW1)
#define D4 37632              // D_IN / 4 float4 per row
#define KS 21                 // K splits (bracketed: 7->265us, 21->219, 42->320)
#define JSTEPS 28             // 588 / 21 (64-float4 steps per chunk)
#define RPW 4                 // rows per wave
#define RPB 16                // rows per block (4 waves)
#define NRB 80                // 1280 / 16
#define NBLK (KS * NRB)       // 1680 = 8 * 210

typedef float f4 __attribute__((ext_vector_type(4)));

// ---------------- stage 1: the 5 batched GEMVs over K=150528 ----------------
// FROZEN at r20's measured config: KS=21, XCD swizzle, 64-reg clean
// (launch_bounds(256,4) = 64-VGPR budget), SGPR row ptrs, per-b xv, NT matrix
// loads (r21 A/B: NT 227 vs plain 247 -- NT protects L2/L3 for the x path;
// HBM byte count is NOT the binding constraint). Only the tail changes.
__global__ __launch_bounds__(256, 4) void stage1(
    const float* __restrict__ x, const float* __restrict__ W1,
    const float* __restrict__ dW1, float* __restrict__ partial) {
  const int bid  = blockIdx.x;                        // 0..1679
  const int vid  = (bid & 7) * (NBLK / 8) + (bid >> 3); // bijective, 1680%8==0
  const int ks   = vid / NRB;                         // 0..20 (XCD-banded)
  const int rb   = vid % NRB;                         // 0..79
  const int wid  = threadIdx.x >> 6;                  // wave 0..3
  const int lane = threadIdx.x & 63;
  // wave-uniform row base -> SGPR
  const int r0   = __builtin_amdgcn_readfirstlane(rb * RPB + wid * RPW);
  const int kb4  = ks * (JSTEPS * 64);                // float4 offset in K

  const f4* rp[RPW];                                  // wave-uniform -> SGPRs
#pragma unroll
  for (int i = 0; i < RPW; ++i) {
    int r = r0 + i, m = r >> 8, f = r & 255;
    const float* base = (m == 0) ? (W1 + (size_t)f * D_IN)
                                 : (dW1 + ((size_t)(m - 1) * FEAT + f) * D_IN);
    rp[i] = (const f4*)base + kb4;
  }
  const f4* x4 = (const f4*)x + kb4;                  // + b*D4 + idx

  float acc[RPW][B];
#pragma unroll
  for (int i = 0; i < RPW; ++i)
#pragma unroll
    for (int b = 0; b < B; ++b) acc[i][b] = 0.f;

  for (int j = 0; j < JSTEPS; ++j) {
    const int idx = j * 64 + lane;
    f4 mv[RPW];
#pragma unroll
    for (int i = 0; i < RPW; ++i)
      mv[i] = __builtin_nontemporal_load(&rp[i][idx]); // 4x 1KB HBM streams
#pragma unroll
    for (int b = 0; b < B; ++b) {                     // one xv live at a time
      f4 xv = x4[(size_t)b * D4 + idx];               // L2-resident (swizzle)
#pragma unroll
      for (int i = 0; i < RPW; ++i)
        acc[i][b] += mv[i][0] * xv[0] + mv[i][1] * xv[1] +
                     mv[i][2] * xv[2] + mv[i][3] * xv[3];
    }
  }

  // full-wave butterfly per (i,b); lanes 0..31 keep (row i=lane>>3, b=lane&7)
  float outv = 0.f;
#pragma unroll
  for (int i = 0; i < RPW; ++i)
#pragma unroll
    for (int b = 0; b < B; ++b) {
      float v = acc[i][b];
      v += __shfl_xor(v, 1);
      v += __shfl_xor(v, 2);
      v += __shfl_xor(v, 4);
      v += __shfl_xor(v, 8);
      v += __shfl_xor(v, 16);
      v += __shfl_xor(v, 32);
      if (lane == i * B + b) outv = v;                // compile-time acc index
    }
  if (lane < RPW * B)                                 // 32 consecutive floats
    partial[((size_t)ks * NROWS + r0) * B + lane] = outv;
}

// ---------------- stage 2: reduce K-splits, add biases (40 blocks) ----------
__global__ __launch_bounds__(256) void stage2(
    const float* __restrict__ partial, const float* __restrict__ b1,
    const float* __restrict__ db1, float* __restrict__ hp) {
  int idx = blockIdx.x * 256 + threadIdx.x;           // 0..10239
  int r = idx >> 3, b = idx & 7;
  int m = r >> 8, f = r & 255;
  float s = (m == 0) ? b1[f] : db1[(m - 1) * FEAT + f];
  for (int ks = 0; ks < KS; ++ks)
    s += partial[((size_t)ks * NROWS + r) * B + b];
  hp[idx] = s;                                        // hp[r][b]
}

// ------ stage 3a: h, base, MetaNet coefs, u — one block per batch (8) -------
__global__ __launch_bounds__(256) void stage3a(
    const float* __restrict__ hp, const float* __restrict__ W2,
    const float* __restrict__ b2, const float* __restrict__ mW1,
    const float* __restrict__ mb1, const float* __restrict__ mW2,
    const float* __restrict__ mb2, float* __restrict__ H,
    float* __restrict__ BASE, float* __restrict__ U, float* __restrict__ C) {
  __shared__ float h_l[FEAT];
  __shared__ float base_l[FEAT];
  __shared__ float mid_l[HID];
  __shared__ float c_l[T];
  const int b = blockIdx.x;
  const int g = threadIdx.x;

  const float hpre = hp[(size_t)g * B + b];
  const float hv = hpre > 0.f ? hpre : 0.f;
  h_l[g] = hv;
  H[b * FEAT + g] = hv;
  __syncthreads();

  const float4* h4 = (const float4*)h_l;
  {
    const float4* w4 = (const float4*)(W2 + (size_t)g * FEAT);
    float s = b2[g];
    for (int f4i = 0; f4i < FEAT / 4; ++f4i) {
      float4 hh = h4[f4i], w = w4[f4i];
      s += hh.x * w.x + hh.y * w.y + hh.z * w.z + hh.w * w.w;
    }
    base_l[g] = s;
    BASE[b * FEAT + g] = s;
  }
  __syncthreads();

  if (g < HID) {
    float s = mb1[g];
    const float4* b4 = (const float4*)base_l;
    const float4* mw = (const float4*)(mW1 + (size_t)g * FEAT);
    for (int f4i = 0; f4i < FEAT / 4; ++f4i) {
      float4 bb = b4[f4i], w = mw[f4i];
      s += bb.x * w.x + bb.y * w.y + bb.z * w.z + bb.w * w.w;
    }
    mid_l[g] = s > 0.f ? s : 0.f;
  }
  __syncthreads();

  if (g < T) {
    float s = mb2[g];
    const float* wrow = mW2 + g * HID;
    for (int hh = 0; hh < HID; ++hh) s += mid_l[hh] * wrow[hh];
    c_l[g] = s;
    C[b * T + g] = s;
  }
  __syncthreads();

  float s = 0.f;
  if (hpre > 0.f) {
#pragma unroll
    for (int t = 0; t < T; ++t)
      s += c_l[t] * hp[((size_t)(1 + t) * FEAT + g) * B + b];
  }
  U[b * FEAT + g] = s;
}

// ------ stage 3b: final combine, 64 blocks (b, g-octant), 8 lanes/output ----
__global__ __launch_bounds__(256) void stage3b(
    const float* __restrict__ H, const float* __restrict__ BASE,
    const float* __restrict__ U, const float* __restrict__ C,
    const float* __restrict__ W2, const float* __restrict__ dW2,
    const float* __restrict__ db2, float* __restrict__ out) {
  __shared__ float h_l[FEAT];
  __shared__ float u_l[FEAT];
  const int b = blockIdx.x;                           // batch
  const int q = blockIdx.y;                           // g-octant 0..7
  const int tid = threadIdx.x;
  h_l[tid] = H[b * FEAT + tid];
  u_l[tid] = U[b * FEAT + tid];
  __syncthreads();
  float c[T];
#pragma unroll
  for (int t = 0; t < T; ++t) c[t] = C[b * T + t];

  const int gl  = tid >> 3;                           // 0..31
  const int sub = tid & 7;                            // lane within g-group
  const int g   = q * 32 + gl;
  const float4* w4 = (const float4*)(W2 + (size_t)g * FEAT);
  const float4* h4 = (const float4*)h_l;
  const float4* u4 = (const float4*)u_l;
  float a1 = 0.f;
  float a2[T] = {0.f, 0.f, 0.f, 0.f};
#pragma unroll
  for (int k = 0; k < 8; ++k) {
    const int f4i = k * 8 + sub;                      // 8 lanes -> 128B runs
    float4 w = w4[f4i], uu = u4[f4i], hh = h4[f4i];
    a1 += uu.x * w.x + uu.y * w.y + uu.z * w.z + uu.w * w.w;
#pragma unroll
    for (int t = 0; t < T; ++t) {
      float4 dv = ((const float4*)(dW2 + (((size_t)t * FEAT) + g) * FEAT))[f4i];
      a2[t] += hh.x * dv.x + hh.y * dv.y + hh.z * dv.z + hh.w * dv.w;
    }
  }
  // reduce across the 8 sub-lanes
#pragma unroll
  for (int off = 1; off < 8; off <<= 1) {
    a1 += __shfl_xor(a1, off, 8);
#pragma unroll
    for (int t = 0; t < T; ++t) a2[t] += __shfl_xor(a2[t], off, 8);
  }
  if (sub == 0) {
    float o = BASE[b * FEAT + g];
#pragma unroll
    for (int t = 0; t < T; ++t) o += c[t] * db2[t * FEAT + g];
    o += a1;
#pragma unroll
    for (int t = 0; t < T; ++t) o += c[t] * a2[t];
    out[b * FEAT + g] = o;
  }
}

extern "C" void kernel_launch(void* const* d_in, const int* in_sizes, int n_in,
                              void* d_out, int out_size, void* d_ws, size_t ws_size,
                              hipStream_t stream) {
  const float* x   = (const float*)d_in[0];
  const float* W1  = (const float*)d_in[1];
  const float* b1  = (const float*)d_in[2];
  const float* W2  = (const float*)d_in[3];
  const float* b2  = (const float*)d_in[4];
  const float* mW1 = (const float*)d_in[5];
  const float* mb1 = (const float*)d_in[6];
  const float* mW2 = (const float*)d_in[7];
  const float* mb2 = (const float*)d_in[8];
  const float* dW1 = (const float*)d_in[9];
  const float* db1 = (const float*)d_in[10];
  const float* dW2 = (const float*)d_in[11];
  const float* db2 = (const float*)d_in[12];
  float* out = (float*)d_out;

  float* ws   = (float*)d_ws;
  float* P    = ws;                              // [21][1280][8] = 215040
  float* HP   = P + (size_t)KS * NROWS * B;      // [1280][8] = 10240
  float* H    = HP + 10240;                      // [8][256]
  float* BASE = H + 2048;                        // [8][256]
  float* U    = BASE + 2048;                     // [8][256]
  float* C    = U + 2048;                        // [8][4]

  stage1<<<NBLK, 256, 0, stream>>>(x, W1, dW1, P);
  stage2<<<40, 256, 0, stream>>>(P, b1, db1, HP);
  stage3a<<<B, 256, 0, stream>>>(HP, W2, b2, mW1, mb1, mW2, mb2, H, BASE, U, C);
  stage3b<<<dim3(B, 8), 256, 0, stream>>>(H, BASE, U, C, W2, dW2, db2, out);
}